// Round 1
// baseline (152.911 us; speedup 1.0000x reference)
//
#include <hip/hip_runtime.h>

#define T_STEPS 20
#define NI 5
#define NH 100
#define NO 3

// One thread per batch element.
// Loop structure: h (hidden unit) OUTER, t (time) INNER fully unrolled.
// Each hidden unit's membrane depends only on its scalar drive c = cur1[b,h],
// so we evolve it standalone and scatter its spike train into cur2 accumulators
// acc[20][3] held in registers. Layer-2 dynamics run afterwards from acc.
//
// Rounding discipline: the reference computes
//   mem = (BETA*mem + cur) - reset*THRESH
// as separate mul/add/sub. We use __fmul_rn/__fadd_rn/__fsub_rn to forbid FMA
// contraction on the recurrences so threshold crossings match; dot products
// (ascending-h accumulation, exact 0/1 products) use FMA.
//
// R1 changes vs baseline (bit-identical arithmetic):
//  - __launch_bounds__(256, 1): baseline reported VGPR_Count=36, which cannot
//    hold the 60-float acc[][] live set -> compiler was round-tripping acc
//    through AGPRs (or worse). Grid gives only 4 waves/SIMD, so up to ~512
//    VGPRs costs no occupancy. Force acc into arch VGPRs.
//  - software prefetch of next h's W1 row / W2 triple / b1 into SGPR-resident
//    locals one full t-loop (~330 cycles) ahead of use, hiding SMEM latency
//    (VALUBusy was 90%, not ~98%).
//  - spf carried as a float across t iterations: exactly one v_cndmask per
//    step serves both the reset subtract (next step) and the 3 acc fmas.
__global__ __launch_bounds__(256, 1) void snn_kernel(
    const float* __restrict__ x,
    const float* __restrict__ W1,
    const float* __restrict__ b1,
    const float* __restrict__ W2,
    const float* __restrict__ b2,
    float* __restrict__ out, int B)
{
    int b = blockIdx.x * blockDim.x + threadIdx.x;
    if (b >= B) return;

    float xv[NI];
#pragma unroll
    for (int i = 0; i < NI; ++i) xv[i] = x[b * NI + i];

    float acc[T_STEPS][NO];
#pragma unroll
    for (int t = 0; t < T_STEPS; ++t)
#pragma unroll
        for (int o = 0; o < NO; ++o) acc[t][o] = 0.0f;

    // Prefetch h=0 weights (wave-uniform -> SGPRs via s_load)
    float b1c = b1[0];
    float w1c[NI];
#pragma unroll
    for (int i = 0; i < NI; ++i) w1c[i] = W1[i];
    float w2c0 = W2[0 * NH + 0];
    float w2c1 = W2[1 * NH + 0];
    float w2c2 = W2[2 * NH + 0];

    for (int h = 0; h < NH; ++h) {
        // cur1[b,h] = x[b,:] . W1[h,:] + b1[h]  (uses weights prefetched last iter)
        float c = b1c;
#pragma unroll
        for (int i = 0; i < NI; ++i) c = __builtin_fmaf(xv[i], w1c[i], c);
        const float w0 = w2c0;
        const float w1 = w2c1;
        const float w2 = w2c2;

        // Prefetch next iteration's weights NOW; s_waitcnt for these lands
        // after the full unrolled t-loop below -> latency fully hidden.
        const int hn = (h + 1 < NH) ? (h + 1) : 0;
        b1c = b1[hn];
#pragma unroll
        for (int i = 0; i < NI; ++i) w1c[i] = W1[hn * NI + i];
        w2c0 = W2[0 * NH + hn];
        w2c1 = W2[1 * NH + hn];
        w2c2 = W2[2 * NH + hn];

        float mem = 0.0f;
        float spf = 0.0f;  // reset value == previous step's spike (as float)
#pragma unroll
        for (int t = 0; t < T_STEPS; ++t) {
            float tmp = __fmul_rn(0.95f, mem);
            tmp = __fadd_rn(tmp, c);
            mem = __fsub_rn(tmp, spf);
            spf = (mem > 1.0f) ? 1.0f : 0.0f;   // == (mem - 1 > 0) exactly in fp32
            acc[t][0] = __builtin_fmaf(spf, w0, acc[t][0]);
            acc[t][1] = __builtin_fmaf(spf, w1, acc[t][1]);
            acc[t][2] = __builtin_fmaf(spf, w2, acc[t][2]);
        }
    }

    // Layer-2 LIF dynamics + spike count
    float b2c[NO];
#pragma unroll
    for (int o = 0; o < NO; ++o) b2c[o] = b2[o];

    float m2[NO]  = {0.0f, 0.0f, 0.0f};
    float cnt[NO] = {0.0f, 0.0f, 0.0f};
    float r2f[NO] = {0.0f, 0.0f, 0.0f};
#pragma unroll
    for (int t = 0; t < T_STEPS; ++t) {
#pragma unroll
        for (int o = 0; o < NO; ++o) {
            float cur = __fadd_rn(acc[t][o], b2c[o]);   // (sum) + b2, ref order
            float tmp = __fmul_rn(0.95f, m2[o]);
            tmp = __fadd_rn(tmp, cur);
            m2[o] = __fsub_rn(tmp, r2f[o]);
            r2f[o] = (m2[o] > 1.0f) ? 1.0f : 0.0f;
            cnt[o] = __fadd_rn(cnt[o], r2f[o]);
        }
    }
#pragma unroll
    for (int o = 0; o < NO; ++o) out[b * NO + o] = cnt[o];
}

extern "C" void kernel_launch(void* const* d_in, const int* in_sizes, int n_in,
                              void* d_out, int out_size, void* d_ws, size_t ws_size,
                              hipStream_t stream) {
    const float* x  = (const float*)d_in[0];
    const float* W1 = (const float*)d_in[1];
    const float* b1 = (const float*)d_in[2];
    const float* W2 = (const float*)d_in[3];
    const float* b2 = (const float*)d_in[4];
    float* out = (float*)d_out;

    int B = in_sizes[0] / NI;  // 262144
    int threads = 256;
    int blocks = (B + threads - 1) / threads;
    snn_kernel<<<blocks, threads, 0, stream>>>(x, W1, b1, W2, b2, out, B);
}

// Round 2
// 140.731 us; speedup vs baseline: 1.0866x; 1.0866x over previous
//
#include <hip/hip_runtime.h>

#define T_STEPS 20
#define NI 5
#define NH 100
#define NO 3

// One thread per batch element.
// Loop structure: h (hidden unit) OUTER, t (time) INNER fully unrolled.
// Each hidden unit's membrane depends only on its scalar drive c = cur1[b,h],
// so we evolve it standalone and scatter its spike train into cur2 accumulators
// acc[20][3] held in registers. Layer-2 dynamics run afterwards from acc.
//
// R2: the compiler was keeping acc[20][3] in AGPRs (VGPR_Count=36/48 across
// R0/R1 — cannot hold the 60-float live set), paying v_accvgpr_read/write
// round-trips around every accumulate: measured ~14.5 VALU/(h,t) vs the 8-op
// source floor. __launch_bounds__ hints did not steer the allocator, so the
// inner t-step is now written as inline asm with "v"-constrained operands
// ("v" = arch VGPR class; AGPR is "a" — the allocator cannot round-trip).
// 8 instructions per (h,t), bit-identical rounding to the reference:
//   mem = fl(fl(0.95*mem) + c) - spf   (separate mul/add/sub, no FMA)
//   sp  = mem > 1.0f                   (v_cmp_lt_f32 vcc, 1.0, mem)
//   acc[t][o] += spf * W2[o,h]         (v_fmac, exact 0/1 products)
__global__ __launch_bounds__(256, 2) void snn_kernel(
    const float* __restrict__ x,
    const float* __restrict__ W1,
    const float* __restrict__ b1,
    const float* __restrict__ W2,
    const float* __restrict__ b2,
    float* __restrict__ out, int B)
{
    int b = blockIdx.x * blockDim.x + threadIdx.x;
    if (b >= B) return;

    float xv[NI];
#pragma unroll
    for (int i = 0; i < NI; ++i) xv[i] = x[b * NI + i];

    float acc[T_STEPS][NO];
#pragma unroll
    for (int t = 0; t < T_STEPS; ++t)
#pragma unroll
        for (int o = 0; o < NO; ++o) acc[t][o] = 0.0f;

    for (int h = 0; h < NH; ++h) {
        // cur1[b,h] = x[b,:] . W1[h,:] + b1[h]   (wave-uniform W1/b1 -> s_load)
        float c = b1[h];
#pragma unroll
        for (int i = 0; i < NI; ++i) c = __builtin_fmaf(xv[i], W1[h * NI + i], c);

        float w0 = W2[0 * NH + h];
        float w1 = W2[1 * NH + h];
        float w2 = W2[2 * NH + h];

        float mem = 0.0f;
        float spf = 0.0f;  // previous step's spike as float (reset amount)
        float tmp;
#pragma unroll
        for (int t = 0; t < T_STEPS; ++t) {
            // 8 VALU ops, arch-VGPR pinned. 0x3F733333 == 0.95f.
            asm volatile(
                "v_mul_f32 %[tmp], 0x3F733333, %[mem]\n\t"
                "v_add_f32 %[tmp], %[tmp], %[c]\n\t"
                "v_sub_f32 %[mem], %[tmp], %[spf]\n\t"
                "v_cmp_lt_f32 vcc, 1.0, %[mem]\n\t"
                "v_cndmask_b32 %[spf], 0, %[one], vcc\n\t"
                "v_fmac_f32 %[A0], %[w0], %[spf]\n\t"
                "v_fmac_f32 %[A1], %[w1], %[spf]\n\t"
                "v_fmac_f32 %[A2], %[w2], %[spf]"
                : [tmp] "=&v"(tmp), [mem] "+v"(mem), [spf] "+v"(spf),
                  [A0] "+v"(acc[t][0]), [A1] "+v"(acc[t][1]), [A2] "+v"(acc[t][2])
                : [c] "v"(c), [w0] "s"(w0), [w1] "s"(w1), [w2] "s"(w2),
                  [one] "v"(1.0f)
                : "vcc");
        }
    }

    // Layer-2 LIF dynamics + spike count (≈2% of runtime, plain C)
    float m2[NO]  = {0.0f, 0.0f, 0.0f};
    float cnt[NO] = {0.0f, 0.0f, 0.0f};
    float r2f[NO] = {0.0f, 0.0f, 0.0f};
#pragma unroll
    for (int t = 0; t < T_STEPS; ++t) {
#pragma unroll
        for (int o = 0; o < NO; ++o) {
            float cur = __fadd_rn(acc[t][o], b2[o]);   // (sum) + b2, ref order
            float tmp2 = __fmul_rn(0.95f, m2[o]);
            tmp2 = __fadd_rn(tmp2, cur);
            m2[o] = __fsub_rn(tmp2, r2f[o]);
            r2f[o] = (m2[o] > 1.0f) ? 1.0f : 0.0f;
            cnt[o] = __fadd_rn(cnt[o], r2f[o]);
        }
    }
#pragma unroll
    for (int o = 0; o < NO; ++o) out[b * NO + o] = cnt[o];
}

extern "C" void kernel_launch(void* const* d_in, const int* in_sizes, int n_in,
                              void* d_out, int out_size, void* d_ws, size_t ws_size,
                              hipStream_t stream) {
    const float* x  = (const float*)d_in[0];
    const float* W1 = (const float*)d_in[1];
    const float* b1 = (const float*)d_in[2];
    const float* W2 = (const float*)d_in[3];
    const float* b2 = (const float*)d_in[4];
    float* out = (float*)d_out;

    int B = in_sizes[0] / NI;  // 262144
    int threads = 256;
    int blocks = (B + threads - 1) / threads;
    snn_kernel<<<blocks, threads, 0, stream>>>(x, W1, b1, W2, b2, out, B);
}

// Round 3
// 138.576 us; speedup vs baseline: 1.1034x; 1.0156x over previous
//
#include <hip/hip_runtime.h>

#define T_STEPS 20
#define NI 5
#define NH 100
#define NO 3

// One thread per batch element; h outer, t inner (fully unrolled, inline asm).
// Each hidden unit's membrane depends only on its scalar drive c = cur1[b,h];
// its spike train is scattered into cur2 accumulators acc[20][3] in VGPRs.
//
// Regime (R2 post-mortem): VALU-issue bound at the power-limited sustained
// clock (~1.57 GHz; matches learn_hip m07's 103/157.3 TF dense-VALU plateau).
// Only lever left: instruction count. R3 trims boundary steps, bit-exactly:
//  - t=0: mem0 = fl(fl(0.95*0)+c)-0 == c exactly -> only cmp/cndmask/3 fmac.
//  - t=1: the mul reads c directly (no mem-init mov).
//  - per-(h,t) core stays the 8-op floor: mul/add/sub (separate roundings to
//    match the reference's non-FMA-contracted recurrence), cmp, cndmask,
//    3x fmac (s*w products exact since s in {0,1}, fmac == mul-then-add here,
//    ascending-h order matches the reference dot).
__global__ __launch_bounds__(256, 2) void snn_kernel(
    const float* __restrict__ x,
    const float* __restrict__ W1,
    const float* __restrict__ b1,
    const float* __restrict__ W2,
    const float* __restrict__ b2,
    float* __restrict__ out, int B)
{
    int b = blockIdx.x * blockDim.x + threadIdx.x;
    if (b >= B) return;

    float xv[NI];
#pragma unroll
    for (int i = 0; i < NI; ++i) xv[i] = x[b * NI + i];

    float acc[T_STEPS][NO];
#pragma unroll
    for (int t = 0; t < T_STEPS; ++t)
#pragma unroll
        for (int o = 0; o < NO; ++o) acc[t][o] = 0.0f;

    const float one = 1.0f;

#pragma unroll 2
    for (int h = 0; h < NH; ++h) {
        // cur1[b,h] = x[b,:] . W1[h,:] + b1[h]   (wave-uniform W1/b1 -> s_load)
        float c = b1[h];
#pragma unroll
        for (int i = 0; i < NI; ++i) c = __builtin_fmaf(xv[i], W1[h * NI + i], c);

        float w0 = W2[0 * NH + h];
        float w1 = W2[1 * NH + h];
        float w2 = W2[2 * NH + h];

        float mem, spf, tmp;

        // t = 0: mem0 == c exactly (0.95*0=0, 0+c=c, c-0=c, all exact).
        asm volatile(
            "v_cmp_lt_f32 vcc, 1.0, %[c]\n\t"
            "v_cndmask_b32 %[spf], 0, %[one], vcc\n\t"
            "v_fmac_f32 %[A0], %[w0], %[spf]\n\t"
            "v_fmac_f32 %[A1], %[w1], %[spf]\n\t"
            "v_fmac_f32 %[A2], %[w2], %[spf]"
            : [spf] "=&v"(spf),
              [A0] "+v"(acc[0][0]), [A1] "+v"(acc[0][1]), [A2] "+v"(acc[0][2])
            : [c] "v"(c), [one] "v"(one),
              [w0] "s"(w0), [w1] "s"(w1), [w2] "s"(w2)
            : "vcc");

        // t = 1: mul reads c directly (mem register not yet needed).
        asm volatile(
            "v_mul_f32 %[tmp], 0x3F733333, %[c]\n\t"
            "v_add_f32 %[tmp], %[tmp], %[c]\n\t"
            "v_sub_f32 %[mem], %[tmp], %[spf]\n\t"
            "v_cmp_lt_f32 vcc, 1.0, %[mem]\n\t"
            "v_cndmask_b32 %[spf], 0, %[one], vcc\n\t"
            "v_fmac_f32 %[A0], %[w0], %[spf]\n\t"
            "v_fmac_f32 %[A1], %[w1], %[spf]\n\t"
            "v_fmac_f32 %[A2], %[w2], %[spf]"
            : [tmp] "=&v"(tmp), [mem] "=&v"(mem), [spf] "+v"(spf),
              [A0] "+v"(acc[1][0]), [A1] "+v"(acc[1][1]), [A2] "+v"(acc[1][2])
            : [c] "v"(c), [one] "v"(one),
              [w0] "s"(w0), [w1] "s"(w1), [w2] "s"(w2)
            : "vcc");

        // t = 2..19: steady-state 8-op step.
#pragma unroll
        for (int t = 2; t < T_STEPS; ++t) {
            asm volatile(
                "v_mul_f32 %[tmp], 0x3F733333, %[mem]\n\t"
                "v_add_f32 %[tmp], %[tmp], %[c]\n\t"
                "v_sub_f32 %[mem], %[tmp], %[spf]\n\t"
                "v_cmp_lt_f32 vcc, 1.0, %[mem]\n\t"
                "v_cndmask_b32 %[spf], 0, %[one], vcc\n\t"
                "v_fmac_f32 %[A0], %[w0], %[spf]\n\t"
                "v_fmac_f32 %[A1], %[w1], %[spf]\n\t"
                "v_fmac_f32 %[A2], %[w2], %[spf]"
                : [tmp] "=&v"(tmp), [mem] "+v"(mem), [spf] "+v"(spf),
                  [A0] "+v"(acc[t][0]), [A1] "+v"(acc[t][1]), [A2] "+v"(acc[t][2])
                : [c] "v"(c), [one] "v"(one),
                  [w0] "s"(w0), [w1] "s"(w1), [w2] "s"(w2)
                : "vcc");
        }
    }

    // Layer-2 LIF dynamics + spike count (~2% of runtime, plain C)
    float m2[NO]  = {0.0f, 0.0f, 0.0f};
    float cnt[NO] = {0.0f, 0.0f, 0.0f};
    float r2f[NO] = {0.0f, 0.0f, 0.0f};
#pragma unroll
    for (int t = 0; t < T_STEPS; ++t) {
#pragma unroll
        for (int o = 0; o < NO; ++o) {
            float cur = __fadd_rn(acc[t][o], b2[o]);   // (sum) + b2, ref order
            float tmp2 = __fmul_rn(0.95f, m2[o]);
            tmp2 = __fadd_rn(tmp2, cur);
            m2[o] = __fsub_rn(tmp2, r2f[o]);
            r2f[o] = (m2[o] > 1.0f) ? 1.0f : 0.0f;
            cnt[o] = __fadd_rn(cnt[o], r2f[o]);
        }
    }
#pragma unroll
    for (int o = 0; o < NO; ++o) out[b * NO + o] = cnt[o];
}

extern "C" void kernel_launch(void* const* d_in, const int* in_sizes, int n_in,
                              void* d_out, int out_size, void* d_ws, size_t ws_size,
                              hipStream_t stream) {
    const float* x  = (const float*)d_in[0];
    const float* W1 = (const float*)d_in[1];
    const float* b1 = (const float*)d_in[2];
    const float* W2 = (const float*)d_in[3];
    const float* b2 = (const float*)d_in[4];
    float* out = (float*)d_out;

    int B = in_sizes[0] / NI;  // 262144
    int threads = 256;
    int blocks = (B + threads - 1) / threads;
    snn_kernel<<<blocks, threads, 0, stream>>>(x, W1, b1, W2, b2, out, B);
}

// Round 4
// 137.337 us; speedup vs baseline: 1.1134x; 1.0090x over previous
//
#include <hip/hip_runtime.h>

#define T_STEPS 20
#define NI 5
#define NH 100
#define NO 3

// One thread per batch element; h outer, t inner (fully unrolled, inline asm).
// Regime (R3 post-mortem): VALU-issue bound; dur implies sustained clock
// ~1.54 GHz = same 64%-of-nominal plateau as m07's pure-FMA ubench -> likely
// power-limited clock, not bubbles. R4 discriminates: 2-iteration software
// pipeline of the wave-uniform weight loads (SALU/SMEM only, zero VALU delta,
// arithmetic instruction-identical to R3). Null result => roofline.
//
// Exactness: mem recurrence via separate v_mul/v_add/v_sub (matches the
// reference's non-contracted fp32 rounding); spike cmp is (1.0 < mem);
// acc fmacs are exact (spf in {0,1}) in ascending-h order. t=0/t=1 peeled
// (mem0 == c exactly; t=1 mul reads c directly).
__device__ __forceinline__ void lif_unit(float c, float w0, float w1, float w2,
                                         float one, float (&acc)[T_STEPS][NO])
{
    float mem, spf, tmp;

    // t = 0: mem0 == c exactly (0.95*0=0, 0+c=c, c-0=c, all exact).
    asm volatile(
        "v_cmp_lt_f32 vcc, 1.0, %[c]\n\t"
        "v_cndmask_b32 %[spf], 0, %[one], vcc\n\t"
        "v_fmac_f32 %[A0], %[w0], %[spf]\n\t"
        "v_fmac_f32 %[A1], %[w1], %[spf]\n\t"
        "v_fmac_f32 %[A2], %[w2], %[spf]"
        : [spf] "=&v"(spf),
          [A0] "+v"(acc[0][0]), [A1] "+v"(acc[0][1]), [A2] "+v"(acc[0][2])
        : [c] "v"(c), [one] "v"(one),
          [w0] "s"(w0), [w1] "s"(w1), [w2] "s"(w2)
        : "vcc");

    // t = 1: mul reads c directly (mem register not yet needed).
    asm volatile(
        "v_mul_f32 %[tmp], 0x3F733333, %[c]\n\t"
        "v_add_f32 %[tmp], %[tmp], %[c]\n\t"
        "v_sub_f32 %[mem], %[tmp], %[spf]\n\t"
        "v_cmp_lt_f32 vcc, 1.0, %[mem]\n\t"
        "v_cndmask_b32 %[spf], 0, %[one], vcc\n\t"
        "v_fmac_f32 %[A0], %[w0], %[spf]\n\t"
        "v_fmac_f32 %[A1], %[w1], %[spf]\n\t"
        "v_fmac_f32 %[A2], %[w2], %[spf]"
        : [tmp] "=&v"(tmp), [mem] "=&v"(mem), [spf] "+v"(spf),
          [A0] "+v"(acc[1][0]), [A1] "+v"(acc[1][1]), [A2] "+v"(acc[1][2])
        : [c] "v"(c), [one] "v"(one),
          [w0] "s"(w0), [w1] "s"(w1), [w2] "s"(w2)
        : "vcc");

    // t = 2..19: steady-state 8-op step.
#pragma unroll
    for (int t = 2; t < T_STEPS; ++t) {
        asm volatile(
            "v_mul_f32 %[tmp], 0x3F733333, %[mem]\n\t"
            "v_add_f32 %[tmp], %[tmp], %[c]\n\t"
            "v_sub_f32 %[mem], %[tmp], %[spf]\n\t"
            "v_cmp_lt_f32 vcc, 1.0, %[mem]\n\t"
            "v_cndmask_b32 %[spf], 0, %[one], vcc\n\t"
            "v_fmac_f32 %[A0], %[w0], %[spf]\n\t"
            "v_fmac_f32 %[A1], %[w1], %[spf]\n\t"
            "v_fmac_f32 %[A2], %[w2], %[spf]"
            : [tmp] "=&v"(tmp), [mem] "+v"(mem), [spf] "+v"(spf),
              [A0] "+v"(acc[t][0]), [A1] "+v"(acc[t][1]), [A2] "+v"(acc[t][2])
            : [c] "v"(c), [one] "v"(one),
              [w0] "s"(w0), [w1] "s"(w1), [w2] "s"(w2)
            : "vcc");
    }
}

__global__ __launch_bounds__(256, 2) void snn_kernel(
    const float* __restrict__ x,
    const float* __restrict__ W1,
    const float* __restrict__ b1,
    const float* __restrict__ W2,
    const float* __restrict__ b2,
    float* __restrict__ out, int B)
{
    int b = blockIdx.x * blockDim.x + threadIdx.x;
    if (b >= B) return;

    float xv[NI];
#pragma unroll
    for (int i = 0; i < NI; ++i) xv[i] = x[b * NI + i];

    float acc[T_STEPS][NO];
#pragma unroll
    for (int t = 0; t < T_STEPS; ++t)
#pragma unroll
        for (int o = 0; o < NO; ++o) acc[t][o] = 0.0f;

    const float one = 1.0f;

    // Software pipeline: weights for units (h, h+1) resident in "cur" slots;
    // (h+2, h+3) prefetched into "nxt" slots before compute consumes cur.
    // All wave-uniform -> SGPRs; rotation is s_mov (scalar pipe, free).
    float cb0 = b1[0], cb1 = b1[1];
    float cW1a[NI], cW1b[NI];
#pragma unroll
    for (int i = 0; i < NI; ++i) { cW1a[i] = W1[i]; cW1b[i] = W1[NI + i]; }
    float cw2a0 = W2[0 * NH + 0], cw2a1 = W2[1 * NH + 0], cw2a2 = W2[2 * NH + 0];
    float cw2b0 = W2[0 * NH + 1], cw2b1 = W2[1 * NH + 1], cw2b2 = W2[2 * NH + 1];

    for (int h = 0; h < NH; h += 2) {
        const int hn = (h + 2 < NH) ? (h + 2) : 0;  // wrap: harmless reload

        // Prefetch next pair's weights NOW; their s_waitcnt lands ~330
        // instructions later (after both lif_units below).
        float nb0 = b1[hn], nb1 = b1[hn + 1];
        float nW1a[NI], nW1b[NI];
#pragma unroll
        for (int i = 0; i < NI; ++i) {
            nW1a[i] = W1[hn * NI + i];
            nW1b[i] = W1[(hn + 1) * NI + i];
        }
        float nw2a0 = W2[0 * NH + hn],     nw2a1 = W2[1 * NH + hn],     nw2a2 = W2[2 * NH + hn];
        float nw2b0 = W2[0 * NH + hn + 1], nw2b1 = W2[1 * NH + hn + 1], nw2b2 = W2[2 * NH + hn + 1];

        // Unit h
        float c0 = cb0;
#pragma unroll
        for (int i = 0; i < NI; ++i) c0 = __builtin_fmaf(xv[i], cW1a[i], c0);
        lif_unit(c0, cw2a0, cw2a1, cw2a2, one, acc);

        // Unit h+1
        float c1 = cb1;
#pragma unroll
        for (int i = 0; i < NI; ++i) c1 = __builtin_fmaf(xv[i], cW1b[i], c1);
        lif_unit(c1, cw2b0, cw2b1, cw2b2, one, acc);

        // Rotate prefetched -> current (scalar moves)
        cb0 = nb0; cb1 = nb1;
#pragma unroll
        for (int i = 0; i < NI; ++i) { cW1a[i] = nW1a[i]; cW1b[i] = nW1b[i]; }
        cw2a0 = nw2a0; cw2a1 = nw2a1; cw2a2 = nw2a2;
        cw2b0 = nw2b0; cw2b1 = nw2b1; cw2b2 = nw2b2;
    }

    // Layer-2 LIF dynamics + spike count (~2% of runtime, plain C)
    float m2[NO]  = {0.0f, 0.0f, 0.0f};
    float cnt[NO] = {0.0f, 0.0f, 0.0f};
    float r2f[NO] = {0.0f, 0.0f, 0.0f};
#pragma unroll
    for (int t = 0; t < T_STEPS; ++t) {
#pragma unroll
        for (int o = 0; o < NO; ++o) {
            float cur = __fadd_rn(acc[t][o], b2[o]);   // (sum) + b2, ref order
            float tmp2 = __fmul_rn(0.95f, m2[o]);
            tmp2 = __fadd_rn(tmp2, cur);
            m2[o] = __fsub_rn(tmp2, r2f[o]);
            r2f[o] = (m2[o] > 1.0f) ? 1.0f : 0.0f;
            cnt[o] = __fadd_rn(cnt[o], r2f[o]);
        }
    }
#pragma unroll
    for (int o = 0; o < NO; ++o) out[b * NO + o] = cnt[o];
}

extern "C" void kernel_launch(void* const* d_in, const int* in_sizes, int n_in,
                              void* d_out, int out_size, void* d_ws, size_t ws_size,
                              hipStream_t stream) {
    const float* x  = (const float*)d_in[0];
    const float* W1 = (const float*)d_in[1];
    const float* b1 = (const float*)d_in[2];
    const float* W2 = (const float*)d_in[3];
    const float* b2 = (const float*)d_in[4];
    float* out = (float*)d_out;

    int B = in_sizes[0] / NI;  // 262144
    int threads = 256;
    int blocks = (B + threads - 1) / threads;
    snn_kernel<<<blocks, threads, 0, stream>>>(x, W1, b1, W2, b2, out, B);
}